// Round 14
// baseline (52.833 us; speedup 1.0000x reference)
//
#include <hip/hip_runtime.h>
#include <hip/hip_bf16.h>
#include <type_traits>

typedef __attribute__((ext_vector_type(4))) float f32x4;
typedef __attribute__((ext_vector_type(8))) short bf16x8;

static constexpr int B_   = 2048;
static constexpr int IN_  = 1024;
static constexpr int HID_ = 2048;
static constexpr int NB_  = 8;
static constexpr int BS_  = 256;   // block size
static constexpr int G3_  = 768;   // 3*BS_

// packed fp32x2 -> bf16x2 RNE, single VALU op (no builtin on gfx950)
__device__ __forceinline__ unsigned cvtpk(float lo, float hi) {
  unsigned r;
  asm("v_cvt_pk_bf16_f32 %0, %1, %2" : "=v"(r) : "v"(lo), "v"(hi));
  return r;
}

// ---------- fully-fused block-GRU MFMA kernel, K-step 32 ----------
// Single launch, no workspace. Tile: 128 rows x 64 out-cols; 4 waves (2x2).
// Accumulators: [0]=r (K=1280 combined), [1]=z (combined), [2]=i_n, [3]=h_n.
// LDS: 2 buffers x 20KB { A [128][32]bf16 @0, W [192][32]bf16 @8192 }.
// SWIZZLE (round-14 fix): 64B rows; phys slot = logical colgrp ^ (r&3) ^ ((r>>2)&3)
// (bits [5:4] ^= row bits [7:6]^[9:8], involution). Frag-read bank-group
// (byte/16 mod 8) = (4(r&1) + c^s(r)) mod 8 -> exactly 2 lanes per group over
// any 16-lane run and 8 per group over the wave => conflict-free (2-way free).
// (Round-13's single-XOR collapsed lanes {0,4,8,12} onto one group: 4-way,
// 3.28M conflict cycles.)
// Staging: 5 passes (A2+W3, 40 VGPR) fp32->cvt_pk->ds_write, issue-early/
// write-late around the compute phase; one __syncthreads per step.
// EPILOGUE (round-14 fix): z/ng staged through LDS (per-wave [32][72] f32
// regions, 2 halves), then 8-lane groups do full-128B-line float4 hprev loads
// and out stores (was: 32 scattered scalar loads+stores per lane).
__global__ __launch_bounds__(256, 2) void gru_mfma(
    const float* __restrict__ xf,     // [2048][1024]
    const float* __restrict__ hf,     // [2048][2048]
    const float* __restrict__ Wih,    // [8][768][1024]
    const float* __restrict__ Whh,    // [8][768][256]
    const float* __restrict__ b_ih,   // [8][768]
    const float* __restrict__ b_hh,   // [8][768]
    float* __restrict__ out)          // [2048][2048]
{
  __shared__ __align__(16) char lds[2][20480];

  const int t    = threadIdx.x;
  const int lane = t & 63;
  const int wid  = t >> 6;
  const int wm   = wid >> 1;     // wave row (0..1) -> 64-row half
  const int wn   = wid & 1;      // wave col (0..1) -> 32-col half

  // Bijective XCD swizzle: nwg=512 = 8 XCDs x 64 -> each XCD owns one GRU block n.
  const int bid = blockIdx.x;
  const int swz = (bid & 7) * 64 + (bid >> 3);
  const int mrow0 = (swz & 15) * 128;
  const int ct    = swz >> 4;
  const int n     = ct >> 2;          // GRU block index
  const int s0    = (ct & 3) * 64;    // col offset within block

  // Staging pass p targets phys offset op = p*4096 + t*16 (region-local);
  // logical ol = op ^ ((((op>>6)&3) ^ ((op>>8)&3)) << 4) (involution).
  int arow[2], acolE[2];
#pragma unroll
  for (int p = 0; p < 2; ++p) {
    int op = p * 4096 + t * 16;
    int sx = ((op >> 6) & 3) ^ ((op >> 8) & 3);
    int ol = op ^ (sx << 4);
    arow[p]  = ol >> 6;           // 0..127
    acolE[p] = (ol & 63) >> 1;    // element offset {0,8,16,24}
  }
  int wgrow[3], wcolE[3];
#pragma unroll
  for (int q = 0; q < 3; ++q) {
    int op = q * 4096 + t * 16;
    int sx = ((op >> 6) & 3) ^ ((op >> 8) & 3);
    int ol = op ^ (sx << 4);
    int wr = ol >> 6;             // 0..191
    wgrow[q]  = n * G3_ + (wr >> 6) * BS_ + s0 + (wr & 63);  // global W row
    wcolE[q]  = (ol & 63) >> 1;
  }

  f32x4 acc[4][4][2] = {};   // [set][mi][ni]
  float4 sa[2][2];           // A staging (16 VGPR)
  float4 sw[3][2];           // W staging (24 VGPR)

  auto issue = [&](int tt) {             // 10 coalesced fp32 loads (40 VGPR)
#pragma unroll
    for (int p = 0; p < 2; ++p) {
      const float* src = (tt < 32)
        ? xf + (size_t)(mrow0 + arow[p]) * IN_  + tt * 32 + acolE[p]
        : hf + (size_t)(mrow0 + arow[p]) * HID_ + n * BS_ + (tt - 32) * 32 + acolE[p];
      sa[p][0] = *reinterpret_cast<const float4*>(src);
      sa[p][1] = *reinterpret_cast<const float4*>(src + 4);
    }
#pragma unroll
    for (int q = 0; q < 3; ++q) {
      const float* src = (tt < 32)
        ? Wih + (size_t)wgrow[q] * IN_ + tt * 32 + wcolE[q]
        : Whh + (size_t)wgrow[q] * BS_ + (tt - 32) * 32 + wcolE[q];
      sw[q][0] = *reinterpret_cast<const float4*>(src);
      sw[q][1] = *reinterpret_cast<const float4*>(src + 4);
    }
  };
  auto pack8 = [&](const float4& a, const float4& b) {
    union { unsigned u[4]; bf16x8 v; } r;
    r.u[0] = cvtpk(a.x, a.y); r.u[1] = cvtpk(a.z, a.w);
    r.u[2] = cvtpk(b.x, b.y); r.u[3] = cvtpk(b.z, b.w);
    return r.v;
  };
  auto writeAll = [&](int buf) {         // cvt + 5 ds_write_b128 (linear phys)
    char* base = (char*)lds[buf];
#pragma unroll
    for (int p = 0; p < 2; ++p)
      *reinterpret_cast<bf16x8*>(base + p * 4096 + t * 16) = pack8(sa[p][0], sa[p][1]);
#pragma unroll
    for (int q = 0; q < 3; ++q)
      *reinterpret_cast<bf16x8*>(base + 8192 + q * 4096 + t * 16) = pack8(sw[q][0], sw[q][1]);
  };

  auto compute = [&](int buf, auto ph1c) {
    constexpr bool PH1 = decltype(ph1c)::value;
    const char* base = (const char*)lds[buf];
    bf16x8 af[4];
#pragma unroll
    for (int mi = 0; mi < 4; ++mi) {
      int ar = wm * 64 + mi * 16 + (lane & 15);
      int sg = (ar & 3) ^ ((ar >> 2) & 3);
      int off = ar * 64 + ((((lane >> 4)) ^ sg) << 4);
      af[mi] = *reinterpret_cast<const bf16x8*>(base + off);
    }
    __builtin_amdgcn_s_setprio(1);
#pragma unroll
    for (int g = 0; g < 3; ++g) {
      bf16x8 wf[2];
#pragma unroll
      for (int ni = 0; ni < 2; ++ni) {
        int wr = g * 64 + wn * 32 + ni * 16 + (lane & 15);
        int sg = (wr & 3) ^ ((wr >> 2) & 3);
        int off = wr * 64 + ((((lane >> 4)) ^ sg) << 4);
        wf[ni] = *reinterpret_cast<const bf16x8*>(base + 8192 + off);
      }
      constexpr int set2 = PH1 ? 2 : 3;
      const int set = (g < 2) ? g : set2;
#pragma unroll
      for (int mi = 0; mi < 4; ++mi)
#pragma unroll
        for (int ni = 0; ni < 2; ++ni)
          acc[set][mi][ni] = __builtin_amdgcn_mfma_f32_16x16x32_bf16(
              af[mi], wf[ni], acc[set][mi][ni], 0, 0, 0);
    }
    __builtin_amdgcn_s_setprio(0);
  };

  // ---- prologue: stage tile 0 into buf0 ----
  issue(0);
  writeAll(0);
  __syncthreads();

  // ---- 40 K-steps (32 input + 8 hidden), fully unrolled, ONE barrier each ----
#pragma unroll
  for (int tt = 0; tt < 40; ++tt) {
    const int cur = tt & 1;

    if (tt < 39) issue(tt + 1);             // T14: issue early
    __builtin_amdgcn_sched_barrier(0);      // loads stay above compute
    if (tt < 32) compute(cur, std::true_type{});
    else         compute(cur, std::false_type{});
    __builtin_amdgcn_sched_barrier(0);      // write-late boundary
    if (tt < 39) writeAll(cur ^ 1);
    __syncthreads();   // writes visible; reads of cur retired; loads consumed
  }
  // Final __syncthreads above: all waves done with K-loop LDS -> reuse as scratch.

  // ---- epilogue: z/ng through LDS, coalesced 128B hprev reads + out writes ----
  // Per wave: [32 rows][72 dwords] region (z at +0, ng at +36), 9216B; 4 waves
  // = 36864B <= 40960B. Two halves (mi 0-1, mi 2-3). Wave-local only.
  float* ew = (float*)lds + wid * 2304;     // 2304 dwords = 9216 B
  const int gc0 = n * BS_ + s0 + wn * 32;

#pragma unroll
  for (int half = 0; half < 2; ++half) {
#pragma unroll
    for (int ml = 0; ml < 2; ++ml) {
      const int mi = half * 2 + ml;
#pragma unroll
      for (int ni = 0; ni < 2; ++ni) {
        int scol = s0 + wn * 32 + ni * 16 + (lane & 15);
        float br_i = b_ih[n * G3_ + 0 * BS_ + scol];
        float bz_i = b_ih[n * G3_ + 1 * BS_ + scol];
        float bn_i = b_ih[n * G3_ + 2 * BS_ + scol];
        float br_h = b_hh[n * G3_ + 0 * BS_ + scol];
        float bz_h = b_hh[n * G3_ + 1 * BS_ + scol];
        float bn_h = b_hh[n * G3_ + 2 * BS_ + scol];
#pragma unroll
        for (int i = 0; i < 4; ++i) {
          float rr = acc[0][mi][ni][i] + br_i + br_h;
          float zz = acc[1][mi][ni][i] + bz_i + bz_h;
          float r  = 1.f / (1.f + __expf(-rr));
          float z  = 1.f / (1.f + __expf(-zz));
          float ng = tanhf(acc[2][mi][ni][i] + bn_i + r * (acc[3][mi][ni][i] + bn_h));
          int lrow = ml * 16 + (lane >> 4) * 4 + i;   // 0..31 (C/D row map)
          int lcol = ni * 16 + (lane & 15);           // 0..31
          ew[lrow * 72 + lcol]      = z;
          ew[lrow * 72 + 36 + lcol] = ng;
        }
      }
    }
    asm volatile("s_waitcnt lgkmcnt(0)");
    __builtin_amdgcn_sched_barrier(0);
#pragma unroll
    for (int p = 0; p < 4; ++p) {
      int lrow = p * 8 + (lane >> 3);                 // 0..31
      int grow = mrow0 + wm * 64 + half * 32 + lrow;
      int cc   = (lane & 7) * 4;
      float4 z4  = *reinterpret_cast<const float4*>(ew + lrow * 72 + cc);
      float4 ng4 = *reinterpret_cast<const float4*>(ew + lrow * 72 + 36 + cc);
      float4 h4  = *reinterpret_cast<const float4*>(hf + (size_t)grow * HID_ + gc0 + cc);
      float4 o4;
      o4.x = (1.f - z4.x) * ng4.x + z4.x * h4.x;
      o4.y = (1.f - z4.y) * ng4.y + z4.y * h4.y;
      o4.z = (1.f - z4.z) * ng4.z + z4.z * h4.z;
      o4.w = (1.f - z4.w) * ng4.w + z4.w * h4.w;
      *reinterpret_cast<float4*>(out + (size_t)grow * HID_ + gc0 + cc) = o4;
    }
    if (half == 0) {
      asm volatile("s_waitcnt lgkmcnt(0)");   // reads done before region reuse
      __builtin_amdgcn_sched_barrier(0);
    }
  }
}

extern "C" void kernel_launch(void* const* d_in, const int* in_sizes, int n_in,
                              void* d_out, int out_size, void* d_ws, size_t ws_size,
                              hipStream_t stream) {
  const float* x   = (const float*)d_in[0];
  const float* h   = (const float*)d_in[1];
  const float* Wih = (const float*)d_in[2];
  const float* Whh = (const float*)d_in[3];
  const float* bih = (const float*)d_in[4];
  const float* bhh = (const float*)d_in[5];
  float* out = (float*)d_out;
  (void)d_ws; (void)ws_size;

  gru_mfma<<<512, 256, 0, stream>>>(x, h, Wih, Whh, bih, bhh, out);
}